// Round 10
// baseline (81.126 us; speedup 1.0000x reference)
//
#include <hip/hip_runtime.h>
#include <hip/hip_bf16.h>
#include <math.h>

typedef __bf16 bf16;
typedef __bf16 bf16x8 __attribute__((ext_vector_type(8)));
typedef float  f32x4  __attribute__((ext_vector_type(4)));

#define NTOK   16384
#define DIN    512
#define DOUT   512
#define NTYPES 128
#define TEBD   128
#define NEXP   8
#define NPAIR  64      // pair key = e0*8+e1 (e0 = top-1, e1 = top-2, always distinct)
#define MAXTILE 192    // sum_l ceil(n_l/128) <= 64 + 16384/128 = 192

// ---- workspace layout (bytes); total ~4.5 MB ----
#define WS_HPART   0                          // int[128][64] transposed partials (32KB)
#define WS_ROUTE_W 32768                      // float2[128] (w0,w1) per type
#define WS_BASET   33792                      // int[128] packed base per type
#define WS_CURS    34304                      // int[128] per-type cursor
#define WS_CNTP    34816                      // int[64]  per-pair count
#define WS_BASEP   35072                      // int[64]  per-pair base (128-ALIGNED)
#define WS_NTILE   35328                      // int[1]
#define WS_TMAP    35840                      // int2[192] (list, r0)
#define WS_RMAP    37888                      // int[192*128] packed row -> token (pads=0)
#define WS_WGT     (WS_RMAP + MAXTILE * 128 * 4)   // float2[192*128]
#define WS_WET     (WS_WGT + MAXTILE * 128 * 8)    // bf16[8*512*512] (4 MB)

#define GLOAD_LDS16(g, l)                                                     \
  __builtin_amdgcn_global_load_lds(                                           \
      (const __attribute__((address_space(1))) void*)(g),                     \
      (__attribute__((address_space(3))) void*)(l), 16, 0, 0)

// ------- per-block type histogram partials, TRANSPOSED [type][block] -------
__global__ void hist_kernel(const int* __restrict__ atype, int* __restrict__ hpart) {
  __shared__ int h[NTYPES];
  int tid = threadIdx.x;
  if (tid < NTYPES) h[tid] = 0;
  __syncthreads();
  int t = blockIdx.x * 256 + tid;
  atomicAdd(&h[atype[t]], 1);
  __syncthreads();
  if (tid < NTYPES) hpart[tid * 64 + blockIdx.x] = h[tid];
}

// ---- route (top-2 softmax per type) + pair scan + tile map, one block -----
// base_pair is 128-ALIGNED so packed tile ti <-> rows [ti*128, ti*128+128).
// Pad rows get row_map=0 (token 0: valid data, masked by nrow in epilogue).
__global__ void route_scan_kernel(const float* __restrict__ emb,
                                  const float* __restrict__ Wg,
                                  const int* __restrict__ hpart,
                                  float* __restrict__ route_w,
                                  int* __restrict__ base_type,
                                  int* __restrict__ cursor,
                                  int* __restrict__ cnt_pair,
                                  int* __restrict__ base_pair,
                                  int* __restrict__ ntile,
                                  int* __restrict__ tmap,
                                  int* __restrict__ row_map) {
  __shared__ int s_cnt[NPAIR];
  __shared__ int s_off[NTYPES];
  __shared__ int s_pair[NTYPES];
  int t = threadIdx.x;  // 128 threads = 128 types
  if (t < NPAIR) s_cnt[t] = 0;
  __syncthreads();

  int myc = 0;
  {
    const int4* hp = (const int4*)(hpart + t * 64);
#pragma unroll
    for (int b = 0; b < 16; ++b) {
      int4 v = hp[b];
      myc += v.x + v.y + v.z + v.w;
    }
  }

  const float* er = emb + (size_t)t * TEBD;
  float lg[NEXP];
#pragma unroll
  for (int e = 0; e < NEXP; ++e) lg[e] = 0.f;
  for (int j = 0; j < TEBD; ++j) {
    float ev = er[j];
#pragma unroll
    for (int e = 0; e < NEXP; ++e) lg[e] += ev * Wg[j * NEXP + e];
  }
  float v0 = -__builtin_inff(), v1 = -__builtin_inff();
  int i0 = 0, i1 = 0;
#pragma unroll
  for (int e = 0; e < NEXP; ++e) {
    float v = lg[e];
    if (v > v0) { v1 = v0; i1 = i0; v0 = v; i0 = e; }
    else if (v > v1) { v1 = v; i1 = e; }
  }
  float d = expf(v1 - v0);
  float inv = 1.f / (1.f + d);
  route_w[t * 2 + 0] = inv;
  route_w[t * 2 + 1] = d * inv;
  int p = i0 * 8 + i1;
  s_pair[t] = p;
  s_off[t] = atomicAdd(&s_cnt[p], myc);
  cursor[t] = 0;
  __syncthreads();

  if (t < NPAIR) {
    int b = 0, tb = 0;
    for (int j = 0; j < t; ++j) {
      int nt_j = (s_cnt[j] + 127) >> 7;
      b += nt_j << 7;          // 128-aligned cumulative base
      tb += nt_j;
    }
    base_pair[t] = b;
    cnt_pair[t] = s_cnt[t];
    int nt_l = (s_cnt[t] + 127) >> 7;
    for (int i = 0; i < nt_l; ++i) {
      tmap[(tb + i) * 2 + 0] = t;
      tmap[(tb + i) * 2 + 1] = i * 128;
    }
    for (int i = s_cnt[t]; i < (nt_l << 7); ++i) row_map[b + i] = 0;
    if (t == NPAIR - 1) ntile[0] = tb + nt_l;
  }
  __syncthreads();
  base_type[t] = base_pair[s_pair[t]] + s_off[t];
}

// ---- fused: place (blocks 0..63) ∥ WeT transpose (blocks 64..575) ---------
__global__ void prep2_kernel(const float* __restrict__ We,
                             const int* __restrict__ atype,
                             const float* __restrict__ route_w,
                             const int* __restrict__ base_type,
                             int* __restrict__ cursor,
                             int* __restrict__ row_map,
                             float* __restrict__ wgt,
                             bf16* __restrict__ WeT) {
  int bx = blockIdx.x;
  int tid = threadIdx.x;
  if (bx < 64) {
    // ---- place: token -> packed row (indices only) ----
    __shared__ int lc[NTYPES];
    __shared__ int lb[NTYPES];
    if (tid < NTYPES) lc[tid] = 0;
    __syncthreads();
    int t = bx * 256 + tid;
    int ty = atype[t];
    int r = atomicAdd(&lc[ty], 1);
    __syncthreads();
    if (tid < NTYPES) lb[tid] = lc[tid] ? atomicAdd(&cursor[tid], lc[tid]) : 0;
    __syncthreads();
    int pos = base_type[ty] + lb[ty] + r;
    row_map[pos] = t;
    ((float2*)wgt)[pos] = ((const float2*)route_w)[ty];
  } else {
    // ---- We[e][k][n] f32 -> WeT[e][n][k] bf16, 64x64 tiles ----
    __shared__ float t[64][65];
    int b2 = bx - 64;         // 512 = 8 experts * 8 * 8 tiles
    int e = b2 >> 6;
    int rem = b2 & 63;
    int kt = (rem >> 3) * 64;
    int nt = (rem & 7) * 64;
    int col = tid & 63;
    int rq = tid >> 6;
#pragma unroll
    for (int r = 0; r < 16; ++r) {
      int row = rq * 16 + r;
      t[row][col] = We[((size_t)e * DIN + kt + row) * DOUT + nt + col];
    }
    __syncthreads();
#pragma unroll
    for (int r = 0; r < 16; ++r) {
      int n = rq * 16 + r;
      WeT[((size_t)e * DOUT + nt + n) * DIN + kt + col] = (bf16)t[col][n];
    }
  }
}

// --------- pair-merged grouped GEMM: A staged as RAW F32 -------------------
// Round-10: the GEMM is invariant (~47-50us) across every staging format
// (R1/R2/R4/R6/R8) and never BW-bound (16% HBM). So stop pre-converting x:
// stage f32 rows of the ORIGINAL x directly into LDS (global_load_lds,
// 6 loads/thread/K-step), convert f32->bf16 in registers after the ds_read
// (~32 casts/wave/iter; VALU was 17% busy). This deletes the 48MB x-cvt
// pass from the serialized pre-pass chain.
// tile: BM=128 x BN=64 x 2 experts, BK=32, 4 waves (2x2), 16x16x32 MFMA.
// 3-buf LDS (A f32 16KB + 2xB bf16 4KB per buffer = 72KB -> 2 blocks/CU),
// stage 2 ahead, counted vmcnt(6) (6 loads/stage).
// A-LDS swizzle: rows are 128B -> chunk c = cs ^ (row&7) spreads the
// ds_read_b128 lanes across all 32 banks (2 lanes/bank = free); the
// global source is pre-swizzled so the linear gload_lds dest matches.
// Epilogue: out = w0*tanh(acc0+b0)+w1*tanh(acc1+b1) (fast exp tanh),
// plain scattered store (each token in exactly one pair list).
__global__ __launch_bounds__(256, 2) void moe_gemm_pair_kernel(
    const float* __restrict__ x, const bf16* __restrict__ WeT,
    const float* __restrict__ be, const int* __restrict__ cnt_pair,
    const int* __restrict__ ntile, const int* __restrict__ tmap,
    const int* __restrict__ row_map, const float* __restrict__ wgt,
    float* __restrict__ out) {
  int nwork = ntile[0] * 8;
  int f = blockIdx.y * 8 + blockIdx.x;
  if (f >= nwork) return;
  // bijective chunked XCD swizzle: 8 col-blocks of a row-tile stay on one
  // XCD so the scattered A rows are fetched once and L2-hit 7 times.
  int q = nwork >> 3, r = nwork & 7;
  int xcd = f & 7, idx = f >> 3;
  int L = (xcd < r ? xcd * (q + 1) : r * (q + 1) + (xcd - r) * q) + idx;
  int ti = L >> 3;
  int cx = L & 7;
  int list = tmap[ti * 2 + 0];
  int r0   = tmap[ti * 2 + 1];
  int e0 = list >> 3, e1 = list & 7;
  int nrow = cnt_pair[list] - r0;
  if (nrow > 128) nrow = 128;
  int c0 = cx * 64;
  int arow0 = ti * 128;     // base_pair is 128-aligned

  __shared__ __align__(16) float Asf[3][128 * 32];  // 48 KB
  __shared__ __align__(16) bf16  B0s[3][64 * 32];   // 12 KB
  __shared__ __align__(16) bf16  B1s[3][64 * 32];   // 12 KB
  __shared__ int   tokS[128];
  __shared__ float w0S[128], w1S[128];
  __shared__ float be0S[64], be1S[64];

  int tid = threadIdx.x;
  int lane = tid & 63, w = tid >> 6;

  // token list / weights / bias first (A staging needs tokS)
  if (tid < 128) {
    int srow = (tid < nrow) ? tid : (nrow - 1);
    tokS[tid] = row_map[arow0 + srow];
    float2 ww = ((const float2*)wgt)[arow0 + srow];
    w0S[tid] = ww.x;
    w1S[tid] = ww.y;
    if (tid < 64) {
      be0S[tid] = be[e0 * DOUT + c0 + tid];
      be1S[tid] = be[e1 * DOUT + c0 + tid];
    }
  }
  __syncthreads();

  // A: 4 issues/thread/K-step. slot = (j*4+w)*64+lane; row = slot>>3 (8
  // chunks of 4 f32 per row); source chunk c = cs ^ (row&7) pre-swizzles
  // the global address so the linear LDS dest ends up XOR-swizzled.
  const float* srcA[4];
#pragma unroll
  for (int j = 0; j < 4; ++j) {
    int slot = (j * 4 + w) * 64 + lane;
    int row = slot >> 3, cs = slot & 7;
    int c = cs ^ (row & 7);
    srcA[j] = x + (size_t)tokS[row] * DIN + c * 4;
  }
  const bf16* srcB0;
  const bf16* srcB1;
  {
    int slot = w * 64 + lane;
    int row = slot >> 2, cs = slot & 3;
    int c = cs ^ ((row >> 1) & 3);
    srcB0 = WeT + ((size_t)e0 * DOUT + c0 + row) * DIN + c * 8;
    srcB1 = WeT + ((size_t)e1 * DOUT + c0 + row) * DIN + c * 8;
  }

  auto stage = [&](int buf) {  // 6 gload_lds per thread, then advance one BK
#pragma unroll
    for (int j = 0; j < 4; ++j) {
      GLOAD_LDS16(srcA[j], &Asf[buf][((j * 4 + w) * 64) * 4]);
      srcA[j] += 32;
    }
    GLOAD_LDS16(srcB0, &B0s[buf][w * 64 * 8]);
    GLOAD_LDS16(srcB1, &B1s[buf][w * 64 * 8]);
    srcB0 += 32;
    srcB1 += 32;
  };

  // prologue: tiles 0 and 1 in flight (12 loads/thread)
  stage(0);
  stage(1);

  f32x4 acc0[4][2], acc1[4][2];
#pragma unroll
  for (int mi = 0; mi < 4; ++mi)
#pragma unroll
    for (int ni = 0; ni < 2; ++ni) { acc0[mi][ni] = (f32x4)0.f; acc1[mi][ni] = (f32x4)0.f; }

  int wm = (w >> 1) * 64;
  int wn = (w & 1) * 32;
  int r16 = lane & 15, g16 = lane >> 4;

  // A fragment: 8 consecutive f32 at k=g16*8 -> chunks 2g16, 2g16+1, each
  // XOR-swizzled by (row&7). Two ds_read_b128 per fragment.
  int offAe[4], offAo[4], offB[2];
#pragma unroll
  for (int i = 0; i < 4; ++i) {
    int rA = wm + i * 16 + r16;
    offAe[i] = rA * 32 + (((2 * g16) ^ (rA & 7)) * 4);
    offAo[i] = rA * 32 + (((2 * g16 + 1) ^ (rA & 7)) * 4);
  }
#pragma unroll
  for (int i = 0; i < 2; ++i) {
    int rB = wn + i * 16 + r16;
    offB[i] = rB * 32 + (g16 ^ ((rB >> 1) & 3)) * 8;
  }

#pragma unroll
  for (int t = 0; t < 16; ++t) {
    // wait for tile t only: leaves tile t+1's 6 loads in flight
    if (t < 15) asm volatile("s_waitcnt vmcnt(6)" ::: "memory");
    else        asm volatile("s_waitcnt vmcnt(0)" ::: "memory");
    __builtin_amdgcn_s_barrier();
    // overwrite buf[(t+2)%3] == buf[(t-1)%3]: all waves passed the barrier,
    // hence finished their iter t-1 ds_reads (MFMA consumed them)
    if (t + 2 < 16) stage((t + 2) % 3);

    int cur = t % 3;
    bf16x8 af[4], b0f[2], b1f[2];
#pragma unroll
    for (int i = 0; i < 4; ++i) {
      float4 fe = *(const float4*)&Asf[cur][offAe[i]];
      float4 fo = *(const float4*)&Asf[cur][offAo[i]];
      bf16x8 a;
      a[0] = (bf16)fe.x; a[1] = (bf16)fe.y; a[2] = (bf16)fe.z; a[3] = (bf16)fe.w;
      a[4] = (bf16)fo.x; a[5] = (bf16)fo.y; a[6] = (bf16)fo.z; a[7] = (bf16)fo.w;
      af[i] = a;
    }
#pragma unroll
    for (int i = 0; i < 2; ++i) b0f[i] = *(const bf16x8*)&B0s[cur][offB[i]];
#pragma unroll
    for (int i = 0; i < 2; ++i) b1f[i] = *(const bf16x8*)&B1s[cur][offB[i]];
    __builtin_amdgcn_s_setprio(1);
#pragma unroll
    for (int mi = 0; mi < 4; ++mi)
#pragma unroll
      for (int ni = 0; ni < 2; ++ni) {
        acc0[mi][ni] = __builtin_amdgcn_mfma_f32_16x16x32_bf16(
            af[mi], b0f[ni], acc0[mi][ni], 0, 0, 0);
        acc1[mi][ni] = __builtin_amdgcn_mfma_f32_16x16x32_bf16(
            af[mi], b1f[ni], acc1[mi][ni], 0, 0, 0);
      }
    __builtin_amdgcn_s_setprio(0);
  }

  // ---- epilogue: out = w0*tanh(acc0+b0) + w1*tanh(acc1+b1), plain store ---
  // fast tanh: tanh(x) = (e^2x - 1)/(e^2x + 1); clamp |x|<=9, one shared rcp
  // per pair; |err| ~1e-6 << bf16-quant absmax 9.8e-3.
#pragma unroll
  for (int mi = 0; mi < 4; ++mi) {
#pragma unroll
    for (int ni = 0; ni < 2; ++ni) {
      f32x4 v0 = acc0[mi][ni];
      f32x4 v1 = acc1[mi][ni];
      int colLocal = wn + ni * 16 + r16;
      float bev0 = be0S[colLocal];
      float bev1 = be1S[colLocal];
#pragma unroll
      for (int r = 0; r < 4; ++r) {
        int lrow = wm + mi * 16 + g16 * 4 + r;
        if (lrow < nrow) {
          float x0 = fminf(9.f, fmaxf(-9.f, v0[r] + bev0)) * 2.885390082f;
          float x1 = fminf(9.f, fmaxf(-9.f, v1[r] + bev1)) * 2.885390082f;
          float e0v, e1v, invd;
          asm("v_exp_f32 %0, %1" : "=v"(e0v) : "v"(x0));  // 2^(2x*log2e)=e^2x
          asm("v_exp_f32 %0, %1" : "=v"(e1v) : "v"(x1));
          float d0 = e0v + 1.f, d1 = e1v + 1.f;
          asm("v_rcp_f32 %0, %1" : "=v"(invd) : "v"(d0 * d1));
          float t0 = (e0v - 1.f) * d1 * invd;
          float t1 = (e1v - 1.f) * d0 * invd;
          out[(size_t)tokS[lrow] * DOUT + c0 + colLocal] =
              t0 * w0S[lrow] + t1 * w1S[lrow];
        }
      }
    }
  }
}

extern "C" void kernel_launch(void* const* d_in, const int* in_sizes, int n_in,
                              void* d_out, int out_size, void* d_ws, size_t ws_size,
                              hipStream_t stream) {
  const float* x    = (const float*)d_in[0];
  const float* emb  = (const float*)d_in[1];
  const int*   aty  = (const int*)d_in[2];
  const float* Wg   = (const float*)d_in[3];
  const float* We   = (const float*)d_in[4];
  const float* be   = (const float*)d_in[5];
  float* out = (float*)d_out;

  char* ws = (char*)d_ws;
  int*   hpart     = (int*)(ws + WS_HPART);
  float* route_w   = (float*)(ws + WS_ROUTE_W);
  int*   base_type = (int*)(ws + WS_BASET);
  int*   cursor    = (int*)(ws + WS_CURS);
  int*   cnt_pair  = (int*)(ws + WS_CNTP);
  int*   base_pair = (int*)(ws + WS_BASEP);
  int*   ntile     = (int*)(ws + WS_NTILE);
  int*   tmap      = (int*)(ws + WS_TMAP);
  int*   row_map   = (int*)(ws + WS_RMAP);
  float* wgt       = (float*)(ws + WS_WGT);
  bf16*  WeT       = (bf16*)(ws + WS_WET);

  hist_kernel<<<64, 256, 0, stream>>>(aty, hpart);
  route_scan_kernel<<<1, 128, 0, stream>>>(emb, Wg, hpart, route_w, base_type,
                                           cursor, cnt_pair, base_pair, ntile,
                                           tmap, row_map);
  // place ∥ WeT transpose in one dispatch
  prep2_kernel<<<64 + 512, 256, 0, stream>>>(We, aty, route_w, base_type,
                                             cursor, row_map, wgt, WeT);
  // every out element written exactly once -> no memset of out needed
  moe_gemm_pair_kernel<<<dim3(8, MAXTILE), 256, 0, stream>>>(
      x, WeT, be, cnt_pair, ntile, tmap, row_map, wgt, out);
}